// Round 2
// baseline (276.447 us; speedup 1.0000x reference)
//
#include <hip/hip_runtime.h>
#include <math.h>

#define H 4096
#define NIN 17
#define H4 (H / 4)                    // 1024
#define NSPLIT 512
#define ROWS_PER_SPLIT (H / NSPLIT)   // 8
#define NSPLIT2 32                    // second-stage split count (512/16)

// d_out layout (fp32): [activout(4), valueout(1), hactiv(4096), hebb_new(4096*4096)]
//   hactiv at element offset 5; hebb at element offset 4101 (4B aligned only).
// Scratch lives inside the hebb output region (overwritten by kC afterwards):
//   partial  at 4104 (byte 16416, 16B aligned): NSPLIT  x H floats (8 MB)
//   partial2 at 4104 + NSPLIT*H = 2101256 (byte 8405024, 16B aligned): NSPLIT2 x H floats
#define OUT_HACTIV_OFF  5
#define OUT_HEBB_OFF    4101
#define OUT_PARTIAL_OFF 4104
#define OUT_PARTIAL2_OFF (OUT_PARTIAL_OFF + NSPLIT * H)

// ---------------------------------------------------------------------------
// Kernel A: split-K column reduction of hidden @ (w + alpha*hebb)
// grid = (4, 512), block = 256. Thread: 4 consecutive cols (float4) x 8 rows,
// fully unrolled -> ~24 independent 16B loads in flight. 8192 waves total.
// ---------------------------------------------------------------------------
__global__ __launch_bounds__(256, 4) void kA(const float* __restrict__ hidden,
                                             const float* __restrict__ w,
                                             const float* __restrict__ alpha,
                                             const float* __restrict__ hebb,
                                             float* __restrict__ partial) {
    const int j4 = blockIdx.x * 256 + threadIdx.x;      // 0..1023 (float4 col index)
    const int r0 = blockIdx.y * ROWS_PER_SPLIT;
    const float4* __restrict__ w4 = (const float4*)w;
    const float4* __restrict__ a4 = (const float4*)alpha;
    const float4* __restrict__ b4 = (const float4*)hebb;
    float4 acc = make_float4(0.f, 0.f, 0.f, 0.f);
#pragma unroll
    for (int r = 0; r < ROWS_PER_SPLIT; ++r) {
        const int i = r0 + r;
        const float hv = hidden[i];                     // wave-uniform -> scalar load
        const int base = i * H4 + j4;
        const float4 wv = w4[base];
        const float4 av = a4[base];
        const float4 bv = b4[base];
        acc.x += hv * (wv.x + av.x * bv.x);
        acc.y += hv * (wv.y + av.y * bv.y);
        acc.z += hv * (wv.z + av.z * bv.z);
        acc.w += hv * (wv.w + av.w * bv.w);
    }
    ((float4*)partial)[blockIdx.y * H4 + j4] = acc;
}

// ---------------------------------------------------------------------------
// Kernel B1: reduce 512 partials -> 32 partials. grid = (4, 32), block = 256.
// Thread: float4 acc over 16 splits, fully coalesced.
// ---------------------------------------------------------------------------
__global__ __launch_bounds__(256) void kB1(const float* __restrict__ partial,
                                           float* __restrict__ partial2) {
    const int j4 = blockIdx.x * 256 + threadIdx.x;      // 0..1023
    const float4* __restrict__ p4 = (const float4*)partial;
    float4 acc = make_float4(0.f, 0.f, 0.f, 0.f);
#pragma unroll
    for (int s = 0; s < NSPLIT / NSPLIT2; ++s) {        // 16
        const float4 v = p4[(blockIdx.y * (NSPLIT / NSPLIT2) + s) * H4 + j4];
        acc.x += v.x; acc.y += v.y; acc.z += v.z; acc.w += v.w;
    }
    ((float4*)partial2)[blockIdx.y * H4 + j4] = acc;
}

// ---------------------------------------------------------------------------
// Kernel B2: finish reduction + x@Wi + bi, tanh -> hactiv. grid = 16, block=256.
// ---------------------------------------------------------------------------
__global__ __launch_bounds__(256) void kB2(const float* __restrict__ x,
                                           const float* __restrict__ Wi,
                                           const float* __restrict__ bi,
                                           const float* __restrict__ partial2,
                                           float* __restrict__ hactiv) {
    const int j = blockIdx.x * 256 + threadIdx.x;       // 0..4095
    float s = bi[j];
#pragma unroll
    for (int k = 0; k < NIN; ++k) s += x[k] * Wi[k * H + j];
#pragma unroll
    for (int sp = 0; sp < NSPLIT2; ++sp) s += partial2[sp * H + j];
    hactiv[j] = tanhf(s);
}

// ---------------------------------------------------------------------------
// Kernel C: hebb_new = (1-eta)*hebb + eta*outer(hidden, hactiv) (blocks 0..65535)
// plus heads (softmax policy + value) in the final extra block.
// grid = 65537, block = 256. Scalar dword streams, coalesced.
// ---------------------------------------------------------------------------
__global__ __launch_bounds__(256) void kC(const float* __restrict__ hebb,
                                          const float* __restrict__ hidden,
                                          const float* __restrict__ eta_p,
                                          const float* __restrict__ Wo,
                                          const float* __restrict__ bo,
                                          const float* __restrict__ Wv,
                                          const float* __restrict__ bv,
                                          float* __restrict__ out) {
    const float* __restrict__ hactiv = out + OUT_HACTIV_OFF;
    float* __restrict__ hebb_out = out + OUT_HEBB_OFF;
    const unsigned nHebbBlocks = (unsigned)(H * (H / 256));   // 65536

    if (blockIdx.x < nHebbBlocks) {
        const unsigned g = blockIdx.x * 256u + threadIdx.x;
        const unsigned i = g >> 12;          // row (uniform within block)
        const unsigned col = g & (H - 1);
        const float eta = eta_p[0];
        hebb_out[g] = (1.f - eta) * hebb[g] + eta * hidden[i] * hactiv[col];
    } else {
        __shared__ float red[5][256];
        float a0 = 0.f, a1 = 0.f, a2 = 0.f, a3 = 0.f, av = 0.f;
        const float4* __restrict__ Wo4 = (const float4*)Wo;
        for (int i = threadIdx.x; i < H; i += 256) {
            const float h = hactiv[i];
            const float4 wo = Wo4[i];
            a0 += h * wo.x;
            a1 += h * wo.y;
            a2 += h * wo.z;
            a3 += h * wo.w;
            av += h * Wv[i];
        }
        red[0][threadIdx.x] = a0;
        red[1][threadIdx.x] = a1;
        red[2][threadIdx.x] = a2;
        red[3][threadIdx.x] = a3;
        red[4][threadIdx.x] = av;
        __syncthreads();
        for (int s = 128; s > 0; s >>= 1) {
            if ((int)threadIdx.x < s) {
#pragma unroll
                for (int k = 0; k < 5; ++k)
                    red[k][threadIdx.x] += red[k][threadIdx.x + s];
            }
            __syncthreads();
        }
        if (threadIdx.x == 0) {
            const float z0 = red[0][0] + bo[0];
            const float z1 = red[1][0] + bo[1];
            const float z2 = red[2][0] + bo[2];
            const float z3 = red[3][0] + bo[3];
            const float m = fmaxf(fmaxf(z0, z1), fmaxf(z2, z3));
            const float e0 = expf(z0 - m);
            const float e1 = expf(z1 - m);
            const float e2 = expf(z2 - m);
            const float e3 = expf(z3 - m);
            const float inv = 1.f / (e0 + e1 + e2 + e3);
            out[0] = e0 * inv;
            out[1] = e1 * inv;
            out[2] = e2 * inv;
            out[3] = e3 * inv;
            out[4] = red[4][0] + bv[0];
        }
    }
}

extern "C" void kernel_launch(void* const* d_in, const int* in_sizes, int n_in,
                              void* d_out, int out_size, void* d_ws, size_t ws_size,
                              hipStream_t stream) {
    const float* x      = (const float*)d_in[0];
    const float* hidden = (const float*)d_in[1];
    const float* hebb   = (const float*)d_in[2];
    const float* Wi     = (const float*)d_in[3];
    const float* bi     = (const float*)d_in[4];
    const float* w      = (const float*)d_in[5];
    const float* alpha  = (const float*)d_in[6];
    const float* eta    = (const float*)d_in[7];
    const float* Wo     = (const float*)d_in[8];
    const float* bo     = (const float*)d_in[9];
    const float* Wv     = (const float*)d_in[10];
    const float* bv     = (const float*)d_in[11];
    float* out = (float*)d_out;

    float* partial  = out + OUT_PARTIAL_OFF;
    float* partial2 = out + OUT_PARTIAL2_OFF;
    float* hactiv   = out + OUT_HACTIV_OFF;

    kA<<<dim3(4, NSPLIT), 256, 0, stream>>>(hidden, w, alpha, hebb, partial);
    kB1<<<dim3(4, NSPLIT2), 256, 0, stream>>>(partial, partial2);
    kB2<<<16, 256, 0, stream>>>(x, Wi, bi, partial2, hactiv);
    kC<<<65537, 256, 0, stream>>>(hebb, hidden, eta, Wo, bo, Wv, bv, out);
}

// Round 4
// 262.885 us; speedup vs baseline: 1.0516x; 1.0516x over previous
//
#include <hip/hip_runtime.h>
#include <math.h>

#define H 4096
#define NIN 17
#define H4 (H / 4)                    // 1024
#define NSPLIT 512
#define ROWS_PER_SPLIT (H / NSPLIT)   // 8
#define NSPLIT2 32                    // second-stage split count (512/16)

typedef float vf4 __attribute__((ext_vector_type(4)));

// d_out layout (fp32): [activout(4), valueout(1), hactiv(4096), hebb_new(4096*4096)]
//   hactiv at element offset 5; hebb at element offset 4101 (4B aligned only).
// Scratch lives inside the hebb output region (overwritten by kC afterwards):
//   partial  at 4104 (byte 16416, 16B aligned): NSPLIT  x H floats (8 MB)
//   partial2 at 4104 + NSPLIT*H: NSPLIT2 x H floats
#define OUT_HACTIV_OFF  5
#define OUT_HEBB_OFF    4101
#define OUT_PARTIAL_OFF 4104
#define OUT_PARTIAL2_OFF (OUT_PARTIAL_OFF + NSPLIT * H)

// ---------------------------------------------------------------------------
// Kernel A: split-K column reduction of hidden @ (w + alpha*hebb).
// grid = 512, block = 256. Block b owns rows [b*8, b*8+8): reads 3 x 128 KB
// FULLY CONTIGUOUS per block; consecutive blocks sweep consecutive addresses
// (copy-ubench pattern). Thread t's columns are fixed {t, t+256, t+512, t+768}
// (float4 granularity) -> 4 vf4 accumulators, no cross-thread reduction.
// Nontemporal loads: pure streaming, no reuse within this kernel.
// ---------------------------------------------------------------------------
__global__ __launch_bounds__(256, 2) void kA(const float* __restrict__ hidden,
                                             const float* __restrict__ w,
                                             const float* __restrict__ alpha,
                                             const float* __restrict__ hebb,
                                             float* __restrict__ partial) {
    const int t = threadIdx.x;
    const int b = blockIdx.x;
    const int r0 = b * ROWS_PER_SPLIT;
    const vf4* __restrict__ w4 = (const vf4*)w;
    const vf4* __restrict__ a4 = (const vf4*)alpha;
    const vf4* __restrict__ b4 = (const vf4*)hebb;

    vf4 acc[4];
#pragma unroll
    for (int k = 0; k < 4; ++k) acc[k] = (vf4)(0.f);

#pragma unroll 2
    for (int r = 0; r < ROWS_PER_SPLIT; ++r) {
        const int i = r0 + r;
        const float hv = hidden[i];                 // wave-uniform -> scalar load
        const int rowbase = i * H4;
#pragma unroll
        for (int k = 0; k < 4; ++k) {
            const int idx = rowbase + t + k * 256;
            const vf4 wv = __builtin_nontemporal_load(&w4[idx]);
            const vf4 av = __builtin_nontemporal_load(&a4[idx]);
            const vf4 bv = __builtin_nontemporal_load(&b4[idx]);
            acc[k] += hv * (wv + av * bv);
        }
    }
    vf4* __restrict__ p4 = (vf4*)partial;
#pragma unroll
    for (int k = 0; k < 4; ++k)
        __builtin_nontemporal_store(acc[k], &p4[(b << 10) + t + k * 256]);
}

// ---------------------------------------------------------------------------
// Kernel B1: reduce 512 partials -> 32 partials. grid = (4, 32), block = 256.
// ---------------------------------------------------------------------------
__global__ __launch_bounds__(256) void kB1(const float* __restrict__ partial,
                                           float* __restrict__ partial2) {
    const int j4 = blockIdx.x * 256 + threadIdx.x;      // 0..1023
    const vf4* __restrict__ p4 = (const vf4*)partial;
    vf4 acc = (vf4)(0.f);
#pragma unroll
    for (int s = 0; s < NSPLIT / NSPLIT2; ++s) {        // 16
        acc += p4[(blockIdx.y * (NSPLIT / NSPLIT2) + s) * H4 + j4];
    }
    ((vf4*)partial2)[blockIdx.y * H4 + j4] = acc;
}

// ---------------------------------------------------------------------------
// Kernel B2: finish reduction + x@Wi + bi, tanh -> hactiv. grid = 16, block=256.
// ---------------------------------------------------------------------------
__global__ __launch_bounds__(256) void kB2(const float* __restrict__ x,
                                           const float* __restrict__ Wi,
                                           const float* __restrict__ bi,
                                           const float* __restrict__ partial2,
                                           float* __restrict__ hactiv) {
    const int j = blockIdx.x * 256 + threadIdx.x;       // 0..4095
    float s = bi[j];
#pragma unroll
    for (int k = 0; k < NIN; ++k) s += x[k] * Wi[k * H + j];
#pragma unroll
    for (int sp = 0; sp < NSPLIT2; ++sp) s += partial2[sp * H + j];
    hactiv[j] = tanhf(s);
}

// ---------------------------------------------------------------------------
// Kernel C: hebb_new = (1-eta)*hebb + eta*outer(hidden, hactiv) (blocks 0..65535)
// plus heads (softmax policy + value) in the final extra block.
// grid = 65537, block = 256. Nontemporal streaming; scalar dword stores
// (hebb_out base is only 4B-aligned), coalesced.
// ---------------------------------------------------------------------------
__global__ __launch_bounds__(256) void kC(const float* __restrict__ hebb,
                                          const float* __restrict__ hidden,
                                          const float* __restrict__ eta_p,
                                          const float* __restrict__ Wo,
                                          const float* __restrict__ bo,
                                          const float* __restrict__ Wv,
                                          const float* __restrict__ bv,
                                          float* __restrict__ out) {
    const float* __restrict__ hactiv = out + OUT_HACTIV_OFF;
    float* __restrict__ hebb_out = out + OUT_HEBB_OFF;
    const unsigned nHebbBlocks = (unsigned)(H * (H / 256));   // 65536

    if (blockIdx.x < nHebbBlocks) {
        const unsigned g = blockIdx.x * 256u + threadIdx.x;
        const unsigned i = g >> 12;          // row (uniform within block)
        const unsigned col = g & (H - 1);
        const float eta = eta_p[0];
        const float hv = __builtin_nontemporal_load(&hebb[g]);
        const float v = (1.f - eta) * hv + eta * hidden[i] * hactiv[col];
        __builtin_nontemporal_store(v, &hebb_out[g]);
    } else {
        __shared__ float red[5][256];
        float a0 = 0.f, a1 = 0.f, a2 = 0.f, a3 = 0.f, av = 0.f;
        const vf4* __restrict__ Wo4 = (const vf4*)Wo;
        for (int i = threadIdx.x; i < H; i += 256) {
            const float h = hactiv[i];
            const vf4 wo = Wo4[i];
            a0 += h * wo.x;
            a1 += h * wo.y;
            a2 += h * wo.z;
            a3 += h * wo.w;
            av += h * Wv[i];
        }
        red[0][threadIdx.x] = a0;
        red[1][threadIdx.x] = a1;
        red[2][threadIdx.x] = a2;
        red[3][threadIdx.x] = a3;
        red[4][threadIdx.x] = av;
        __syncthreads();
        for (int s = 128; s > 0; s >>= 1) {
            if ((int)threadIdx.x < s) {
#pragma unroll
                for (int k = 0; k < 5; ++k)
                    red[k][threadIdx.x] += red[k][threadIdx.x + s];
            }
            __syncthreads();
        }
        if (threadIdx.x == 0) {
            const float z0 = red[0][0] + bo[0];
            const float z1 = red[1][0] + bo[1];
            const float z2 = red[2][0] + bo[2];
            const float z3 = red[3][0] + bo[3];
            const float m = fmaxf(fmaxf(z0, z1), fmaxf(z2, z3));
            const float e0 = expf(z0 - m);
            const float e1 = expf(z1 - m);
            const float e2 = expf(z2 - m);
            const float e3 = expf(z3 - m);
            const float inv = 1.f / (e0 + e1 + e2 + e3);
            out[0] = e0 * inv;
            out[1] = e1 * inv;
            out[2] = e2 * inv;
            out[3] = e3 * inv;
            out[4] = red[4][0] + bv[0];
        }
    }
}

extern "C" void kernel_launch(void* const* d_in, const int* in_sizes, int n_in,
                              void* d_out, int out_size, void* d_ws, size_t ws_size,
                              hipStream_t stream) {
    const float* x      = (const float*)d_in[0];
    const float* hidden = (const float*)d_in[1];
    const float* hebb   = (const float*)d_in[2];
    const float* Wi     = (const float*)d_in[3];
    const float* bi     = (const float*)d_in[4];
    const float* w      = (const float*)d_in[5];
    const float* alpha  = (const float*)d_in[6];
    const float* eta    = (const float*)d_in[7];
    const float* Wo     = (const float*)d_in[8];
    const float* bo     = (const float*)d_in[9];
    const float* Wv     = (const float*)d_in[10];
    const float* bv     = (const float*)d_in[11];
    float* out = (float*)d_out;

    float* partial  = out + OUT_PARTIAL_OFF;
    float* partial2 = out + OUT_PARTIAL2_OFF;
    float* hactiv   = out + OUT_HACTIV_OFF;

    kA<<<NSPLIT, 256, 0, stream>>>(hidden, w, alpha, hebb, partial);
    kB1<<<dim3(4, NSPLIT2), 256, 0, stream>>>(partial, partial2);
    kB2<<<16, 256, 0, stream>>>(x, Wi, bi, partial2, hactiv);
    kC<<<65537, 256, 0, stream>>>(hebb, hidden, eta, Wo, bo, Wv, bv, out);
}